// Round 17
// baseline (505.732 us; speedup 1.0000x reference)
//
#include <hip/hip_runtime.h>
#include <math.h>

typedef __attribute__((ext_vector_type(8))) short short8;   // 8 bf16 (4 VGPR) MFMA A/B frag
typedef __attribute__((ext_vector_type(4))) float f32x4;    // MFMA C/D frag
typedef __attribute__((ext_vector_type(4))) uint  uint4v;

constexpr int Bb = 1024, Nn = 100, Hh = 4, Oo = 32, Dd = 128;
constexpr int K1 = 12800, N1 = 1024, M1 = 1024, SK = 8;

#define SEL_L 0x07060302u   /* perm: high ushorts of (b,a) -> packed trunc-bf16 pair */
#define LOG2E 1.44269504f

// bf16 round-to-nearest-even helpers (cold paths only)
__device__ __forceinline__ ushort f2bf(float f) {
    uint u = __float_as_uint(f);
    return (ushort)((u + 0x7FFFu + ((u >> 16) & 1u)) >> 16);
}
__device__ __forceinline__ float bf2f(ushort h) {
    return __uint_as_float(((uint)h) << 16);
}
__device__ __forceinline__ short8 mk8(uint a, uint b, uint c, uint d) {
    uint4v v = {a, b, c, d};
    return __builtin_bit_cast(short8, v);
}
// trunc-split a pair of floats -> packed hi-pair and lo-pair (6 VALU per pair)
__device__ __forceinline__ void tsplit2(float v0, float v1, uint& hp, uint& lp) {
    uint u0 = __float_as_uint(v0), u1 = __float_as_uint(v1);
    float r0 = v0 - __uint_as_float(u0 & 0xFFFF0000u);
    float r1 = v1 - __uint_as_float(u1 & 0xFFFF0000u);
    hp = __builtin_amdgcn_perm(u1, u0, SEL_L);
    lp = __builtin_amdgcn_perm(__float_as_uint(r1), __float_as_uint(r0), SEL_L);
}
// swizzle within [rows][256B] LDS tiles: XOR 16B-slot bits with row&7
__device__ __forceinline__ int swzb(int row, int kb)  { return row * 256 + (kb ^ ((row & 7) << 4)); }

// GAT LDS layout (dynamic, 36352 B)
#define OFF_HTH 0        /* hT hi [32][256B] */
#define OFF_HTL 8192
#define OFF_WTH 16384    /* WT hi [32][256B] */
#define OFF_WTL 24576
#define OFF_AB  32768    /* adjacency bitmask [112][4 u32] (448 words, >=400 zeroed) */
#define OFF_ASV 34560    /* a-vector 64 f32 (pre-scaled by log2 e) */
#define OFF_ESV 34816    /* e_src [128] f32 */
#define OFF_EDV 35328    /* e_dst [128] f32 */
#define OFF_INV 35840    /* 1/rowsum [128] f32 */
#define GAT_LDS 36352

// ---------------------------------------------------------------------------
// pack_A: adjacency -> 128-bit masks, once per b (not per head).
// ---------------------------------------------------------------------------
__global__ __launch_bounds__(256) void pack_A(const float* __restrict__ A, uint* __restrict__ AW)
{
    const int b = blockIdx.x;
    const float4* Ab = (const float4*)(A + (size_t)b * 10000);
    for (int t = threadIdx.x; t < 400; t += 256) {
        const int row = t >> 2, word = t & 3;
        uint bits = 0;
        if (word < 3) {
            #pragma unroll
            for (int j = 0; j < 8; ++j) {
                float4 v = Ab[row * 25 + word * 8 + j];
                uint b4 = (v.x > 0.f ? 1u : 0u) | (v.y > 0.f ? 2u : 0u)
                        | (v.z > 0.f ? 4u : 0u) | (v.w > 0.f ? 8u : 0u);
                bits |= b4 << (j * 4);
            }
        } else {
            float4 v = Ab[row * 25 + 24];   // cols 96..99; 100..127 stay 0
            bits = (v.x > 0.f ? 1u : 0u) | (v.y > 0.f ? 2u : 0u)
                 | (v.z > 0.f ? 4u : 0u) | (v.w > 0.f ? 8u : 0u);
        }
        AW[(size_t)b * 400 + t] = bits;
    }
}

// ---------------------------------------------------------------------------
// Fused GAT layer v3.4: 448 threads = 7 waves, ALL active (no idle wave).
//   per (b, head) block, 3 barriers; in-register P -> MFMA-2.
// ---------------------------------------------------------------------------
template<int F, int KD>
__global__ __launch_bounds__(448, 4) void gat_fused(
    const float* __restrict__ xin,   // [B][100][F]
    const uint*  __restrict__ AW,    // [B][100][4] packed adjacency
    const float* __restrict__ W,     // [H][F][32]
    const float* __restrict__ av,    // [H][64]
    float* __restrict__ xout)        // [B][100][128]
{
    extern __shared__ char smem[];
    char*  HTH = smem + OFF_HTH;
    char*  HTL = smem + OFF_HTL;
    char*  WTH = smem + OFF_WTH;
    char*  WTL = smem + OFF_WTL;
    uint*  ABu = (uint*)(smem + OFF_AB);
    float* ASV = (float*)(smem + OFF_ASV);
    float* ESV = (float*)(smem + OFF_ESV);
    float* EDV = (float*)(smem + OFF_EDV);
    float* INV = (float*)(smem + OFF_INV);

    const int tid = threadIdx.x;
    // XCD-grouped swizzle: 4 head-blocks of one b land on one XCD, adjacent slots
    const int task = (blockIdx.x & 7) * 512 + (blockIdx.x >> 3);
    const int b = task >> 2, hd = task & 3;
    const int w = tid >> 6, lane = tid & 63;
    const int c16 = lane & 15, r16 = lane >> 4;

    const float* xg = xin + (size_t)b * Nn * F;

    if (F == 65) {   // zero WT for k-padding (f 65..95): 1024 u32x4 chunks
        uint4 z = make_uint4(0, 0, 0, 0);
        for (int id = tid; id < 1024; id += 448)
            *(uint4*)(smem + OFF_WTH + id * 16) = z;
        __syncthreads();
    }

    // ---- prefetch x fragments (F=128 path) before the staging barrier
    const int nA = w * 16 + c16;     // < 112; clamp to 99 for loads
    const int nAc = (nA < 100) ? nA : 99;
    float4 xpre[8];
    if (F == 128) {
        #pragma unroll
        for (int d = 0; d < 4; ++d) {
            const float* px = xg + (size_t)nAc * 128 + d * 32 + r16 * 8;
            xpre[2 * d]     = *(const float4*)(px);
            xpre[2 * d + 1] = *(const float4*)(px + 4);
        }
    }

    // ---- ph1: stage WT (RNE hi/lo, transposed; cold), ASV (pre-scaled), AB, zero tails
    {
        const float4* Wg4 = (const float4*)(W + (size_t)hd * F * 32);
        for (int id = tid; id < F * 8; id += 448) {
            int f = id >> 3, o4 = (id & 7) * 4;
            float4 v = Wg4[id];
            ushort h0 = f2bf(v.x), l0 = f2bf(v.x - bf2f(h0));
            ushort h1 = f2bf(v.y), l1 = f2bf(v.y - bf2f(h1));
            ushort h2 = f2bf(v.z), l2 = f2bf(v.z - bf2f(h2));
            ushort h3 = f2bf(v.w), l3 = f2bf(v.w - bf2f(h3));
            *(ushort*)(WTH + swzb(o4 + 0, 2 * f)) = h0; *(ushort*)(WTL + swzb(o4 + 0, 2 * f)) = l0;
            *(ushort*)(WTH + swzb(o4 + 1, 2 * f)) = h1; *(ushort*)(WTL + swzb(o4 + 1, 2 * f)) = l1;
            *(ushort*)(WTH + swzb(o4 + 2, 2 * f)) = h2; *(ushort*)(WTL + swzb(o4 + 2, 2 * f)) = l2;
            *(ushort*)(WTH + swzb(o4 + 3, 2 * f)) = h3; *(ushort*)(WTL + swzb(o4 + 3, 2 * f)) = l3;
        }
    }
    if (tid < 64) ASV[tid] = av[hd * 64 + tid] * LOG2E;   // fold exp->exp2 scale
    if (tid < 400) ABu[tid] = AW[(size_t)b * 400 + tid];
    else           ABu[tid] = 0u;                          // words 400..447 (rows 100..111)
    if (tid < 256) {    // zero hT cols 96..127 (96..99 rewritten in ph2)
        char* base = (tid & 128) ? HTL : HTH;
        const int rr = (tid >> 2) & 31, sl = 12 + (tid & 3);
        *(uint4*)(base + swzb(rr, sl * 16)) = make_uint4(0, 0, 0, 0);
    }
    if (tid >= 416 && tid < 444) { ESV[tid - 316] = 0.f; EDV[tid - 316] = 0.f; }  // idx 100..127
    __syncthreads();

    // ---- ph2: MFMA-1 h = x*W (wave w owns rows w*16..+15, both o-halves)
    {
        f32x4 acc0 = {0.f, 0.f, 0.f, 0.f}, acc1 = {0.f, 0.f, 0.f, 0.f};
        #pragma unroll
        for (int d = 0; d < KD; ++d) {
            float xv[8];
            if (F == 128) {
                float4 v0 = xpre[2 * d], v1 = xpre[2 * d + 1];
                xv[0] = v0.x; xv[1] = v0.y; xv[2] = v0.z; xv[3] = v0.w;
                xv[4] = v1.x; xv[5] = v1.y; xv[6] = v1.z; xv[7] = v1.w;
            } else {
                const int f0 = d * 32 + r16 * 8;
                #pragma unroll
                for (int j = 0; j < 8; ++j) {
                    int f = f0 + j;
                    xv[j] = (f < 65) ? xg[(size_t)nAc * 65 + f] : 0.f;
                }
            }
            uint hu[4], lu[4];
            tsplit2(xv[0], xv[1], hu[0], lu[0]);
            tsplit2(xv[2], xv[3], hu[1], lu[1]);
            tsplit2(xv[4], xv[5], hu[2], lu[2]);
            tsplit2(xv[6], xv[7], hu[3], lu[3]);
            short8 ah = mk8(hu[0], hu[1], hu[2], hu[3]);
            short8 al = mk8(lu[0], lu[1], lu[2], lu[3]);
            const int kb = d * 64 + r16 * 16;
            short8 bh0 = *(const short8*)(WTH + swzb(c16, kb));
            short8 bl0 = *(const short8*)(WTL + swzb(c16, kb));
            short8 bh1 = *(const short8*)(WTH + swzb(16 + c16, kb));
            short8 bl1 = *(const short8*)(WTL + swzb(16 + c16, kb));
            acc0 = __builtin_amdgcn_mfma_f32_16x16x32_bf16(ah, bh0, acc0, 0, 0, 0);
            acc0 = __builtin_amdgcn_mfma_f32_16x16x32_bf16(al, bh0, acc0, 0, 0, 0);
            acc0 = __builtin_amdgcn_mfma_f32_16x16x32_bf16(ah, bl0, acc0, 0, 0, 0);
            acc1 = __builtin_amdgcn_mfma_f32_16x16x32_bf16(ah, bh1, acc1, 0, 0, 0);
            acc1 = __builtin_amdgcn_mfma_f32_16x16x32_bf16(al, bh1, acc1, 0, 0, 0);
            acc1 = __builtin_amdgcn_mfma_f32_16x16x32_bf16(ah, bl1, acc1, 0, 0, 0);
        }
        const int n0 = w * 16 + r16 * 4;
        if (n0 < 100) {   // hT trunc-split write: rows o, cols n0..n0+3
            uint2 uh, ul;
            tsplit2(acc0[0], acc0[1], uh.x, ul.x);
            tsplit2(acc0[2], acc0[3], uh.y, ul.y);
            *(uint2*)(HTH + swzb(c16, 2 * n0)) = uh;
            *(uint2*)(HTL + swzb(c16, 2 * n0)) = ul;
            tsplit2(acc1[0], acc1[1], uh.x, ul.x);
            tsplit2(acc1[2], acc1[3], uh.y, ul.y);
            *(uint2*)(HTH + swzb(16 + c16, 2 * n0)) = uh;
            *(uint2*)(HTL + swzb(16 + c16, 2 * n0)) = ul;
        }
        // es/ed: reduce acc*a over 32 o's (both halves pre-summed, 16-lane xor)
        const float as0 = ASV[c16], as1 = ASV[16 + c16];
        const float ad0 = ASV[32 + c16], ad1 = ASV[48 + c16];
        #pragma unroll
        for (int r = 0; r < 4; ++r) {
            float vs = acc0[r] * as0 + acc1[r] * as1;
            float vd = acc0[r] * ad0 + acc1[r] * ad1;
            #pragma unroll
            for (int mk = 1; mk <= 8; mk <<= 1) {
                vs += __shfl_xor(vs, mk, 64);
                vd += __shfl_xor(vd, mk, 64);
            }
            if (c16 == 0 && n0 + r < 100) { ESV[n0 + r] = vs; EDV[n0 + r] = vd; }
        }
    }
    __syncthreads();

    // ---- ph3a: in-register P (exp2, trunc-split), MFMA-2; rowsum -> INV (LDS)
    f32x4 acc0 = {0.f, 0.f, 0.f, 0.f}, acc1 = {0.f, 0.f, 0.f, 0.f};
    {
        const int np = w * 16 + c16;            // P-row this lane supplies (<=111)
        const float esn = ESV[np];
        const uint4 abv = *(const uint4*)(ABu + np * 4);
        float rowsum = 0.f;
        #pragma unroll
        for (int d = 0; d < 4; ++d) {
            const uint wrd = (d == 0) ? abv.x : (d == 1) ? abv.y : (d == 2) ? abv.z : abv.w;
            const float4 ea = *(const float4*)(EDV + d * 32 + r16 * 8);
            const float4 eb = *(const float4*)(EDV + d * 32 + r16 * 8 + 4);
            float p0, p1, p2, p3, p4, p5, p6, p7, e;
            e = esn + ea.x; e = fmaxf(e, 0.2f * e); p0 = ((wrd >> (r16 * 8 + 0)) & 1u) ? exp2f(e) : 0.f;
            e = esn + ea.y; e = fmaxf(e, 0.2f * e); p1 = ((wrd >> (r16 * 8 + 1)) & 1u) ? exp2f(e) : 0.f;
            e = esn + ea.z; e = fmaxf(e, 0.2f * e); p2 = ((wrd >> (r16 * 8 + 2)) & 1u) ? exp2f(e) : 0.f;
            e = esn + ea.w; e = fmaxf(e, 0.2f * e); p3 = ((wrd >> (r16 * 8 + 3)) & 1u) ? exp2f(e) : 0.f;
            e = esn + eb.x; e = fmaxf(e, 0.2f * e); p4 = ((wrd >> (r16 * 8 + 4)) & 1u) ? exp2f(e) : 0.f;
            e = esn + eb.y; e = fmaxf(e, 0.2f * e); p5 = ((wrd >> (r16 * 8 + 5)) & 1u) ? exp2f(e) : 0.f;
            e = esn + eb.z; e = fmaxf(e, 0.2f * e); p6 = ((wrd >> (r16 * 8 + 6)) & 1u) ? exp2f(e) : 0.f;
            e = esn + eb.w; e = fmaxf(e, 0.2f * e); p7 = ((wrd >> (r16 * 8 + 7)) & 1u) ? exp2f(e) : 0.f;
            rowsum += p0 + p1 + p2 + p3 + p4 + p5 + p6 + p7;
            uint h01, l01, h23, l23, h45, l45, h67, l67;
            tsplit2(p0, p1, h01, l01);
            tsplit2(p2, p3, h23, l23);
            tsplit2(p4, p5, h45, l45);
            tsplit2(p6, p7, h67, l67);
            short8 ph = mk8(h01, h23, h45, h67);
            short8 pl = mk8(l01, l23, l45, l67);
            const int kb = d * 64 + r16 * 16;
            short8 bh0 = *(const short8*)(HTH + swzb(c16, kb));
            short8 bl0 = *(const short8*)(HTL + swzb(c16, kb));
            short8 bh1 = *(const short8*)(HTH + swzb(16 + c16, kb));
            short8 bl1 = *(const short8*)(HTL + swzb(16 + c16, kb));
            acc0 = __builtin_amdgcn_mfma_f32_16x16x32_bf16(ph, bh0, acc0, 0, 0, 0);
            acc0 = __builtin_amdgcn_mfma_f32_16x16x32_bf16(ph, bl0, acc0, 0, 0, 0);
            acc0 = __builtin_amdgcn_mfma_f32_16x16x32_bf16(pl, bh0, acc0, 0, 0, 0);
            acc1 = __builtin_amdgcn_mfma_f32_16x16x32_bf16(ph, bh1, acc1, 0, 0, 0);
            acc1 = __builtin_amdgcn_mfma_f32_16x16x32_bf16(ph, bl1, acc1, 0, 0, 0);
            acc1 = __builtin_amdgcn_mfma_f32_16x16x32_bf16(pl, bh1, acc1, 0, 0, 0);
        }
        rowsum += __shfl_xor(rowsum, 16, 64);
        rowsum += __shfl_xor(rowsum, 32, 64);
        if (r16 == 0 && np < 100) INV[np] = 1.0f / rowsum;
    }
    __syncthreads();

    // ---- ph3b: epilogue elu(acc * inv) -> global fp32
    {
        const int n0 = w * 16 + r16 * 4;
        float* xo = xout + (size_t)b * Nn * Dd + hd * 32;
        #pragma unroll
        for (int r = 0; r < 4; ++r) {
            const int n = n0 + r;
            if (n < 100) {
                const float inv = INV[n];
                float v0 = acc0[r] * inv; v0 = v0 > 0.f ? v0 : expm1f(v0);
                float v1 = acc1[r] * inv; v1 = v1 > 0.f ? v1 : expm1f(v1);
                xo[(size_t)n * Dd + c16] = v0;
                xo[(size_t)n * Dd + 16 + c16] = v1;
            }
        }
    }
}

// ---------------------------------------------------------------------------
// GEMM1 split-bf16 MFMA (R15-exact): 128x128 tile, BK=64, SK=8,
// 1-deep in-place prefetch, trunc-split staging.
// ---------------------------------------------------------------------------
#define G1_LDS 73728
__device__ __forceinline__ int aofs(int r, int kb) { return r * 144 + kb; }
__device__ __forceinline__ int bofs(int n, int kb) { return n * 144 + (kb ^ (((n >> 3) & 1) << 4)); }

__global__ __launch_bounds__(512, 4) void gemm1_mfma(
    const float* __restrict__ Ag, const float* __restrict__ Bg,
    float* __restrict__ part)
{
    extern __shared__ char sm[];
    char* AH = sm;             // [128][144]
    char* AL = sm + 18432;
    char* BH = sm + 36864;     // [128][144]
    char* BL = sm + 55296;

    const int tid = threadIdx.x;
    const int pb = blockIdx.x;
    const int task = (pb & 7) * 64 + (pb >> 3);
    const int mb = task & 7, g = task >> 3;
    const int nb = g & 7, z = g >> 3;
    const int m0 = mb * 128, n0 = nb * 128;
    const int k0 = z * 1600;

    const int w = tid >> 6, lane = tid & 63;
    const int wn = w & 3, wm = w >> 2;               // wave tile 64m x 32n
    const int c16 = lane & 15, r16 = lane >> 4;

    const int ra = tid >> 2, kq = tid & 3;           // A: row, 16-k quarter
    const int bn = tid >> 2, kq4 = tid & 3;          // B: col n, 16-k quarter

    const float* Aptr = Ag + (size_t)(m0 + ra) * K1 + k0 + kq * 16;
    const float* Bptr = Bg + (size_t)(k0 + kq4 * 16) * N1 + n0 + bn;

    f32x4 acc[4][2];
    #pragma unroll
    for (int i = 0; i < 4; ++i)
        #pragma unroll
        for (int j = 0; j < 2; ++j) acc[i][j] = (f32x4){0.f, 0.f, 0.f, 0.f};

    float a_reg[16];
    float bR[16];
    #pragma unroll
    for (int q = 0; q < 4; ++q) *(float4*)&a_reg[q * 4] = *(const float4*)(Aptr + q * 4);
    #pragma unroll
    for (int j = 0; j < 16; ++j) bR[j] = Bptr[(size_t)j * N1];

    for (int it = 0; it < 25; ++it) {
        __syncthreads();   // previous iter's MFMA reads done -> LDS writable
        {   // A staging: trunc split + perm pack
            uint hi[8], lo[8];
            #pragma unroll
            for (int i = 0; i < 8; ++i) tsplit2(a_reg[2 * i], a_reg[2 * i + 1], hi[i], lo[i]);
            const int ab = aofs(ra, kq * 32);   // aofs has no XOR: +16 safe
            *(uint4*)(AH + ab)      = make_uint4(hi[0], hi[1], hi[2], hi[3]);
            *(uint4*)(AH + ab + 16) = make_uint4(hi[4], hi[5], hi[6], hi[7]);
            *(uint4*)(AL + ab)      = make_uint4(lo[0], lo[1], lo[2], lo[3]);
            *(uint4*)(AL + ab + 16) = make_uint4(lo[4], lo[5], lo[6], lo[7]);
        }
        {   // B staging: trunc split + perm pack (swizzle-aware per-16B)
            uint hi[8], lo[8];
            #pragma unroll
            for (int i = 0; i < 8; ++i) tsplit2(bR[2 * i], bR[2 * i + 1], hi[i], lo[i]);
            const int bb0 = bofs(bn, kq4 * 32);
            const int bb1 = bofs(bn, kq4 * 32 + 16);
            *(uint4*)(BH + bb0) = make_uint4(hi[0], hi[1], hi[2], hi[3]);
            *(uint4*)(BH + bb1) = make_uint4(hi[4], hi[5], hi[6], hi[7]);
            *(uint4*)(BL + bb0) = make_uint4(lo[0], lo[1], lo[2], lo[3]);
            *(uint4*)(BL + bb1) = make_uint4(lo[4], lo[5], lo[6], lo[7]);
        }
        __syncthreads();   // LDS tile ready

        if (it < 24) {     // prefetch next iter into the same regs
            const int off = (it + 1) * 64;
            #pragma unroll
            for (int q = 0; q < 4; ++q) *(float4*)&a_reg[q * 4] = *(const float4*)(Aptr + off + q * 4);
            #pragma unroll
            for (int j = 0; j < 16; ++j) bR[j] = Bptr[(size_t)(off + j) * N1];
        }

        #pragma unroll
        for (int ks = 0; ks < 2; ++ks) {
            const int kb = ks * 64 + r16 * 16;
            short8 bh[2], bl[2];
            #pragma unroll
            for (int nf = 0; nf < 2; ++nf) {
                const int nr = wn * 32 + nf * 16 + c16;
                bh[nf] = *(const short8*)(BH + bofs(nr, kb));
                bl[nf] = *(const short8*)(BL + bofs(nr, kb));
            }
            #pragma unroll
            for (int mf = 0; mf < 4; ++mf) {
                const int ar = wm * 64 + mf * 16 + c16;
                short8 ah = *(const short8*)(AH + aofs(ar, kb));
                short8 al = *(const short8*)(AL + aofs(ar, kb));
                #pragma unroll
                for (int nf = 0; nf < 2; ++nf) {
                    acc[mf][nf] = __builtin_amdgcn_mfma_f32_16x16x32_bf16(ah, bh[nf], acc[mf][nf], 0, 0, 0);
                    acc[mf][nf] = __builtin_amdgcn_mfma_f32_16x16x32_bf16(al, bh[nf], acc[mf][nf], 0, 0, 0);
                    acc[mf][nf] = __builtin_amdgcn_mfma_f32_16x16x32_bf16(ah, bl[nf], acc[mf][nf], 0, 0, 0);
                }
            }
        }
    }

    float* pz = part + (size_t)z * M1 * N1;
    #pragma unroll
    for (int mf = 0; mf < 4; ++mf) {
        const int m = m0 + wm * 64 + mf * 16 + r16 * 4;
        #pragma unroll
        for (int nf = 0; nf < 2; ++nf) {
            const int n = n0 + wn * 32 + nf * 16 + c16;
            #pragma unroll
            for (int r = 0; r < 4; ++r)
                pz[(size_t)(m + r) * N1 + n] = acc[mf][nf][r];
        }
    }
}

// Reduce split-K partials + bias + BN(eval) + ReLU
__global__ __launch_bounds__(256) void bn1_reduce(
    const float* __restrict__ part, const float* __restrict__ pb1,
    const float* __restrict__ g1, const float* __restrict__ be1,
    float* __restrict__ y1)
{
    const int idx = blockIdx.x * 256 + threadIdx.x;
    float s = 0.f;
    #pragma unroll
    for (int z = 0; z < SK; ++z) s += part[(size_t)z * M1 * N1 + idx];
    const int j = idx & (N1 - 1);
    s += pb1[j];
    const float rbn = 1.0f / sqrtf(1.0f + 1e-5f);
    s = g1[j] * s * rbn + be1[j];
    y1[idx] = fmaxf(s, 0.f);
}

// GEMM2 (1024x1024)x(1024x128) + bias + BN + ReLU -> d_out
__global__ __launch_bounds__(128) void gemm2_bn(
    const float* __restrict__ y1, const float* __restrict__ W2,
    const float* __restrict__ pb2, const float* __restrict__ g2,
    const float* __restrict__ be2, float* __restrict__ out)
{
    __shared__ __align__(16) float xr[1024];
    const int tid = threadIdx.x, m = blockIdx.x;
    for (int i = tid; i < 1024; i += 128) xr[i] = y1[(size_t)m * 1024 + i];
    __syncthreads();
    float acc = 0.f;
    #pragma unroll 8
    for (int k = 0; k < 1024; ++k) acc += xr[k] * W2[k * 128 + tid];
    acc += pb2[tid];
    const float rbn = 1.0f / sqrtf(1.0f + 1e-5f);
    acc = g2[tid] * acc * rbn + be2[tid];
    out[(size_t)m * 128 + tid] = fmaxf(acc, 0.f);
}

// ---------------------------------------------------------------------------
extern "C" void kernel_launch(void* const* d_in, const int* in_sizes, int n_in,
                              void* d_out, int out_size, void* d_ws, size_t ws_size,
                              hipStream_t stream)
{
    const float* X   = (const float*)d_in[0];
    const float* A   = (const float*)d_in[1];
    const float* W0  = (const float*)d_in[2];
    const float* a0  = (const float*)d_in[3];
    const float* Wl  = (const float*)d_in[4];
    const float* al  = (const float*)d_in[5];
    const float* pW1 = (const float*)d_in[6];
    const float* pb1 = (const float*)d_in[7];
    const float* g1  = (const float*)d_in[8];
    const float* be1 = (const float*)d_in[9];
    const float* pW2 = (const float*)d_in[10];
    const float* pb2 = (const float*)d_in[11];
    const float* g2  = (const float*)d_in[12];
    const float* be2 = (const float*)d_in[13];
    float* out = (float*)d_out;

    // ws: xa(52.4MB) | xb(52.4MB, reused as gemm1 partials) | y1(4.2MB, AW overlay)
    float* ws = (float*)d_ws;
    float* xa = ws;
    float* xb = xa + (size_t)Bb * Nn * Dd;
    float* y1 = xb + (size_t)Bb * Nn * Dd;
    float* part = xb;
    uint*  AW = (uint*)y1;          // packed adjacency, dead before bn1 writes y1

    (void)hipFuncSetAttribute(reinterpret_cast<const void*>(gat_fused<65, 3>),
                              hipFuncAttributeMaxDynamicSharedMemorySize, GAT_LDS);
    (void)hipFuncSetAttribute(reinterpret_cast<const void*>(gat_fused<128, 4>),
                              hipFuncAttributeMaxDynamicSharedMemorySize, GAT_LDS);
    (void)hipFuncSetAttribute(reinterpret_cast<const void*>(gemm1_mfma),
                              hipFuncAttributeMaxDynamicSharedMemorySize, G1_LDS);

    pack_A<<<dim3(Bb), 256, 0, stream>>>(A, AW);
    gat_fused<65, 3><<<dim3(Bb * Hh), 448, GAT_LDS, stream>>>(X, AW, W0, a0, xa);
    const float* src = xa; float* dst = xb;
    for (int l = 1; l < 5; ++l) {
        gat_fused<128, 4><<<dim3(Bb * Hh), 448, GAT_LDS, stream>>>(
            src, AW, Wl + (size_t)(l - 1) * Hh * Dd * Oo, al + (size_t)(l - 1) * Hh * 2 * Oo, dst);
        float* t = (float*)src; src = dst; dst = t;
    }
    // after 4 swaps final GAT output is xa; xb free for partials
    gemm1_mfma<<<dim3(512), 512, G1_LDS, stream>>>(xa, pW1, part);
    bn1_reduce<<<dim3((M1 * N1) / 256), 256, 0, stream>>>(part, pb1, g1, be1, y1);
    gemm2_bn<<<dim3(M1), 128, 0, stream>>>(y1, pW2, pb2, g2, be2, out);
}

// Round 18
// 457.517 us; speedup vs baseline: 1.1054x; 1.1054x over previous
//
#include <hip/hip_runtime.h>
#include <math.h>

typedef __attribute__((ext_vector_type(8))) short short8;   // 8 bf16 (4 VGPR) MFMA A/B frag
typedef __attribute__((ext_vector_type(4))) float f32x4;    // MFMA C/D frag
typedef __attribute__((ext_vector_type(4))) uint  uint4v;

constexpr int Bb = 1024, Nn = 100, Hh = 4, Oo = 32, Dd = 128;
constexpr int K1 = 12800, N1 = 1024, M1 = 1024, SK = 8;

#define SEL_L 0x07060302u   /* perm: high ushorts of (b,a) -> packed trunc-bf16 pair */
#define LOG2E 1.44269504f

// bf16 round-to-nearest-even helpers (cold paths only)
__device__ __forceinline__ ushort f2bf(float f) {
    uint u = __float_as_uint(f);
    return (ushort)((u + 0x7FFFu + ((u >> 16) & 1u)) >> 16);
}
__device__ __forceinline__ float bf2f(ushort h) {
    return __uint_as_float(((uint)h) << 16);
}
__device__ __forceinline__ short8 mk8(uint a, uint b, uint c, uint d) {
    uint4v v = {a, b, c, d};
    return __builtin_bit_cast(short8, v);
}
// trunc-split a pair of floats -> packed hi-pair and lo-pair (6 VALU per pair)
__device__ __forceinline__ void tsplit2(float v0, float v1, uint& hp, uint& lp) {
    uint u0 = __float_as_uint(v0), u1 = __float_as_uint(v1);
    float r0 = v0 - __uint_as_float(u0 & 0xFFFF0000u);
    float r1 = v1 - __uint_as_float(u1 & 0xFFFF0000u);
    hp = __builtin_amdgcn_perm(u1, u0, SEL_L);
    lp = __builtin_amdgcn_perm(__float_as_uint(r1), __float_as_uint(r0), SEL_L);
}
// swizzle within [rows][256B] LDS tiles: XOR 16B-slot bits with row&7
__device__ __forceinline__ int swzb(int row, int kb)  { return row * 256 + (kb ^ ((row & 7) << 4)); }

// GAT LDS layout (dynamic, 35840 B)
#define OFF_HTH 0        /* hT hi [32][256B] */
#define OFF_HTL 8192
#define OFF_WTH 16384    /* WT hi [32][256B] */
#define OFF_WTL 24576
#define OFF_AB  32768    /* adjacency bitmask [112][4 u32] (448 words, >=400 zeroed) */
#define OFF_ASV 34560    /* a-vector 64 f32 (pre-scaled by log2 e) */
#define OFF_ESV 34816    /* e_src [128] f32 */
#define OFF_EDV 35328    /* e_dst [128] f32 */
#define GAT_LDS 35840

// ---------------------------------------------------------------------------
// pack_A: adjacency -> 128-bit masks, once per b (not per head).
// ---------------------------------------------------------------------------
__global__ __launch_bounds__(256) void pack_A(const float* __restrict__ A, uint* __restrict__ AW)
{
    const int b = blockIdx.x;
    const float4* Ab = (const float4*)(A + (size_t)b * 10000);
    for (int t = threadIdx.x; t < 400; t += 256) {
        const int row = t >> 2, word = t & 3;
        uint bits = 0;
        if (word < 3) {
            #pragma unroll
            for (int j = 0; j < 8; ++j) {
                float4 v = Ab[row * 25 + word * 8 + j];
                uint b4 = (v.x > 0.f ? 1u : 0u) | (v.y > 0.f ? 2u : 0u)
                        | (v.z > 0.f ? 4u : 0u) | (v.w > 0.f ? 8u : 0u);
                bits |= b4 << (j * 4);
            }
        } else {
            float4 v = Ab[row * 25 + 24];   // cols 96..99; 100..127 stay 0
            bits = (v.x > 0.f ? 1u : 0u) | (v.y > 0.f ? 2u : 0u)
                 | (v.z > 0.f ? 4u : 0u) | (v.w > 0.f ? 8u : 0u);
        }
        AW[(size_t)b * 400 + t] = bits;
    }
}

// ---------------------------------------------------------------------------
// Fused GAT layer v3.5 (= R15 v3.2 + shuffle-broadcast inv, 2 barriers):
//   per (b, head) block, 512 thr; in-register P -> MFMA-2.
// ---------------------------------------------------------------------------
template<int F, int KD>
__global__ __launch_bounds__(512, 4) void gat_fused(
    const float* __restrict__ xin,   // [B][100][F]
    const uint*  __restrict__ AW,    // [B][100][4] packed adjacency
    const float* __restrict__ W,     // [H][F][32]
    const float* __restrict__ av,    // [H][64]
    float* __restrict__ xout)        // [B][100][128]
{
    extern __shared__ char smem[];
    char*  HTH = smem + OFF_HTH;
    char*  HTL = smem + OFF_HTL;
    char*  WTH = smem + OFF_WTH;
    char*  WTL = smem + OFF_WTL;
    uint*  ABu = (uint*)(smem + OFF_AB);
    float* ASV = (float*)(smem + OFF_ASV);
    float* ESV = (float*)(smem + OFF_ESV);
    float* EDV = (float*)(smem + OFF_EDV);

    const int tid = threadIdx.x;
    // XCD-grouped swizzle: 4 head-blocks of one b land on one XCD, adjacent slots
    const int task = (blockIdx.x & 7) * 512 + (blockIdx.x >> 3);
    const int b = task >> 2, hd = task & 3;
    const int w = tid >> 6, lane = tid & 63;
    const int c16 = lane & 15, r16 = lane >> 4;

    const float* xg = xin + (size_t)b * Nn * F;

    if (F == 65) {   // zero WT for k-padding (f 65..95)
        uint4 z = make_uint4(0, 0, 0, 0);
        #pragma unroll
        for (int i = 0; i < 2; ++i)
            *(uint4*)(smem + OFF_WTH + (i * 512 + tid) * 16) = z;
        __syncthreads();
    }

    // ---- prefetch x fragments (F=128 path) before the staging barrier
    const int nA = (w * 16 + c16 < 100) ? (w * 16 + c16) : 99;
    float4 xpre[8];
    if (F == 128 && w < 7) {
        #pragma unroll
        for (int d = 0; d < 4; ++d) {
            const float* px = xg + (size_t)nA * 128 + d * 32 + r16 * 8;
            xpre[2 * d]     = *(const float4*)(px);
            xpre[2 * d + 1] = *(const float4*)(px + 4);
        }
    }

    // ---- ph1: stage WT (RNE hi/lo, transposed; cold), ASV (pre-scaled), AB, zero tails
    {
        const float4* Wg4 = (const float4*)(W + (size_t)hd * F * 32);
        #pragma unroll
        for (int it = 0; it < 2; ++it) {
            int id = it * 512 + tid;            // F*8 chunks (f, o4)
            if (id < F * 8) {
                int f = id >> 3, o4 = (id & 7) * 4;
                float4 v = Wg4[id];
                ushort h0 = f2bf(v.x), l0 = f2bf(v.x - bf2f(h0));
                ushort h1 = f2bf(v.y), l1 = f2bf(v.y - bf2f(h1));
                ushort h2 = f2bf(v.z), l2 = f2bf(v.z - bf2f(h2));
                ushort h3 = f2bf(v.w), l3 = f2bf(v.w - bf2f(h3));
                *(ushort*)(WTH + swzb(o4 + 0, 2 * f)) = h0; *(ushort*)(WTL + swzb(o4 + 0, 2 * f)) = l0;
                *(ushort*)(WTH + swzb(o4 + 1, 2 * f)) = h1; *(ushort*)(WTL + swzb(o4 + 1, 2 * f)) = l1;
                *(ushort*)(WTH + swzb(o4 + 2, 2 * f)) = h2; *(ushort*)(WTL + swzb(o4 + 2, 2 * f)) = l2;
                *(ushort*)(WTH + swzb(o4 + 3, 2 * f)) = h3; *(ushort*)(WTL + swzb(o4 + 3, 2 * f)) = l3;
            }
        }
    }
    if (tid < 64) ASV[tid] = av[hd * 64 + tid] * LOG2E;   // fold exp->exp2 scale
    {
        const int idA = tid - 64;
        if (idA >= 0 && idA < 400) ABu[idA] = AW[(size_t)b * 400 + idA];
        else if (idA >= 400 && idA < 448) ABu[idA] = 0u;   // rows 100..111 -> mask 0
    }
    if (tid < 256) {    // zero hT cols 96..127 (96..99 rewritten in ph2)
        char* base = (tid & 128) ? HTL : HTH;
        const int rr = (tid >> 2) & 31, sl = 12 + (tid & 3);
        *(uint4*)(base + swzb(rr, sl * 16)) = make_uint4(0, 0, 0, 0);
    }
    if (tid < 28) { ESV[100 + tid] = 0.f; EDV[100 + tid] = 0.f; }
    __syncthreads();

    // ---- ph2: MFMA-1 h = x*W (wave w owns rows w*16..+15, both o-halves)
    if (w < 7) {
        f32x4 acc0 = {0.f, 0.f, 0.f, 0.f}, acc1 = {0.f, 0.f, 0.f, 0.f};
        #pragma unroll
        for (int d = 0; d < KD; ++d) {
            float xv[8];
            if (F == 128) {
                float4 v0 = xpre[2 * d], v1 = xpre[2 * d + 1];
                xv[0] = v0.x; xv[1] = v0.y; xv[2] = v0.z; xv[3] = v0.w;
                xv[4] = v1.x; xv[5] = v1.y; xv[6] = v1.z; xv[7] = v1.w;
            } else {
                const int f0 = d * 32 + r16 * 8;
                #pragma unroll
                for (int j = 0; j < 8; ++j) {
                    int f = f0 + j;
                    xv[j] = (f < 65) ? xg[(size_t)nA * 65 + f] : 0.f;
                }
            }
            uint hu[4], lu[4];
            tsplit2(xv[0], xv[1], hu[0], lu[0]);
            tsplit2(xv[2], xv[3], hu[1], lu[1]);
            tsplit2(xv[4], xv[5], hu[2], lu[2]);
            tsplit2(xv[6], xv[7], hu[3], lu[3]);
            short8 ah = mk8(hu[0], hu[1], hu[2], hu[3]);
            short8 al = mk8(lu[0], lu[1], lu[2], lu[3]);
            const int kb = d * 64 + r16 * 16;
            short8 bh0 = *(const short8*)(WTH + swzb(c16, kb));
            short8 bl0 = *(const short8*)(WTL + swzb(c16, kb));
            short8 bh1 = *(const short8*)(WTH + swzb(16 + c16, kb));
            short8 bl1 = *(const short8*)(WTL + swzb(16 + c16, kb));
            acc0 = __builtin_amdgcn_mfma_f32_16x16x32_bf16(ah, bh0, acc0, 0, 0, 0);
            acc0 = __builtin_amdgcn_mfma_f32_16x16x32_bf16(al, bh0, acc0, 0, 0, 0);
            acc0 = __builtin_amdgcn_mfma_f32_16x16x32_bf16(ah, bl0, acc0, 0, 0, 0);
            acc1 = __builtin_amdgcn_mfma_f32_16x16x32_bf16(ah, bh1, acc1, 0, 0, 0);
            acc1 = __builtin_amdgcn_mfma_f32_16x16x32_bf16(al, bh1, acc1, 0, 0, 0);
            acc1 = __builtin_amdgcn_mfma_f32_16x16x32_bf16(ah, bl1, acc1, 0, 0, 0);
        }
        const int n0 = w * 16 + r16 * 4;
        if (n0 < 100) {   // hT trunc-split write: rows o, cols n0..n0+3
            uint2 uh, ul;
            tsplit2(acc0[0], acc0[1], uh.x, ul.x);
            tsplit2(acc0[2], acc0[3], uh.y, ul.y);
            *(uint2*)(HTH + swzb(c16, 2 * n0)) = uh;
            *(uint2*)(HTL + swzb(c16, 2 * n0)) = ul;
            tsplit2(acc1[0], acc1[1], uh.x, ul.x);
            tsplit2(acc1[2], acc1[3], uh.y, ul.y);
            *(uint2*)(HTH + swzb(16 + c16, 2 * n0)) = uh;
            *(uint2*)(HTL + swzb(16 + c16, 2 * n0)) = ul;
        }
        // es/ed: reduce acc*a over 32 o's (both halves pre-summed, 16-lane xor)
        const float as0 = ASV[c16], as1 = ASV[16 + c16];
        const float ad0 = ASV[32 + c16], ad1 = ASV[48 + c16];
        #pragma unroll
        for (int r = 0; r < 4; ++r) {
            float vs = acc0[r] * as0 + acc1[r] * as1;
            float vd = acc0[r] * ad0 + acc1[r] * ad1;
            #pragma unroll
            for (int mk = 1; mk <= 8; mk <<= 1) {
                vs += __shfl_xor(vs, mk, 64);
                vd += __shfl_xor(vd, mk, 64);
            }
            if (c16 == 0 && n0 + r < 100) { ESV[n0 + r] = vs; EDV[n0 + r] = vd; }
        }
    }
    __syncthreads();

    // ---- ph3: in-register P (exp2, trunc-split), MFMA-2, shuffle-broadcast inv
    if (w < 7) {
        f32x4 acc0 = {0.f, 0.f, 0.f, 0.f}, acc1 = {0.f, 0.f, 0.f, 0.f};
        const int np = w * 16 + c16;            // P-row this lane supplies (<=111)
        const float esn = ESV[np];
        const uint4 abv = *(const uint4*)(ABu + np * 4);
        float rowsum = 0.f;
        #pragma unroll
        for (int d = 0; d < 4; ++d) {
            const uint wrd = (d == 0) ? abv.x : (d == 1) ? abv.y : (d == 2) ? abv.z : abv.w;
            const float4 ea = *(const float4*)(EDV + d * 32 + r16 * 8);
            const float4 eb = *(const float4*)(EDV + d * 32 + r16 * 8 + 4);
            float p0, p1, p2, p3, p4, p5, p6, p7, e;
            e = esn + ea.x; e = fmaxf(e, 0.2f * e); p0 = ((wrd >> (r16 * 8 + 0)) & 1u) ? exp2f(e) : 0.f;
            e = esn + ea.y; e = fmaxf(e, 0.2f * e); p1 = ((wrd >> (r16 * 8 + 1)) & 1u) ? exp2f(e) : 0.f;
            e = esn + ea.z; e = fmaxf(e, 0.2f * e); p2 = ((wrd >> (r16 * 8 + 2)) & 1u) ? exp2f(e) : 0.f;
            e = esn + ea.w; e = fmaxf(e, 0.2f * e); p3 = ((wrd >> (r16 * 8 + 3)) & 1u) ? exp2f(e) : 0.f;
            e = esn + eb.x; e = fmaxf(e, 0.2f * e); p4 = ((wrd >> (r16 * 8 + 4)) & 1u) ? exp2f(e) : 0.f;
            e = esn + eb.y; e = fmaxf(e, 0.2f * e); p5 = ((wrd >> (r16 * 8 + 5)) & 1u) ? exp2f(e) : 0.f;
            e = esn + eb.z; e = fmaxf(e, 0.2f * e); p6 = ((wrd >> (r16 * 8 + 6)) & 1u) ? exp2f(e) : 0.f;
            e = esn + eb.w; e = fmaxf(e, 0.2f * e); p7 = ((wrd >> (r16 * 8 + 7)) & 1u) ? exp2f(e) : 0.f;
            rowsum += p0 + p1 + p2 + p3 + p4 + p5 + p6 + p7;
            uint h01, l01, h23, l23, h45, l45, h67, l67;
            tsplit2(p0, p1, h01, l01);
            tsplit2(p2, p3, h23, l23);
            tsplit2(p4, p5, h45, l45);
            tsplit2(p6, p7, h67, l67);
            short8 ph = mk8(h01, h23, h45, h67);
            short8 pl = mk8(l01, l23, l45, l67);
            const int kb = d * 64 + r16 * 16;
            short8 bh0 = *(const short8*)(HTH + swzb(c16, kb));
            short8 bl0 = *(const short8*)(HTL + swzb(c16, kb));
            short8 bh1 = *(const short8*)(HTH + swzb(16 + c16, kb));
            short8 bl1 = *(const short8*)(HTL + swzb(16 + c16, kb));
            acc0 = __builtin_amdgcn_mfma_f32_16x16x32_bf16(ph, bh0, acc0, 0, 0, 0);
            acc0 = __builtin_amdgcn_mfma_f32_16x16x32_bf16(ph, bl0, acc0, 0, 0, 0);
            acc0 = __builtin_amdgcn_mfma_f32_16x16x32_bf16(pl, bh0, acc0, 0, 0, 0);
            acc1 = __builtin_amdgcn_mfma_f32_16x16x32_bf16(ph, bh1, acc1, 0, 0, 0);
            acc1 = __builtin_amdgcn_mfma_f32_16x16x32_bf16(ph, bl1, acc1, 0, 0, 0);
            acc1 = __builtin_amdgcn_mfma_f32_16x16x32_bf16(pl, bh1, acc1, 0, 0, 0);
        }
        // full row-sum for row np (uniform across r16 groups after the two xors)
        rowsum += __shfl_xor(rowsum, 16, 64);
        rowsum += __shfl_xor(rowsum, 32, 64);
        const float invp = 1.0f / rowsum;       // inf for rows>=100, never consumed

        // ---- epilogue: inv via width-16 shuffle (source lane c16' = r16*4+r)
        const int n0 = w * 16 + r16 * 4;
        float* xo = xout + (size_t)b * Nn * Dd + hd * 32;
        #pragma unroll
        for (int r = 0; r < 4; ++r) {
            const int n = n0 + r;
            const float inv = __shfl(invp, r16 * 4 + r, 16);
            if (n < 100) {
                float v0 = acc0[r] * inv; v0 = v0 > 0.f ? v0 : expm1f(v0);
                float v1 = acc1[r] * inv; v1 = v1 > 0.f ? v1 : expm1f(v1);
                xo[(size_t)n * Dd + c16] = v0;
                xo[(size_t)n * Dd + 16 + c16] = v1;
            }
        }
    }
}

// ---------------------------------------------------------------------------
// GEMM1 split-bf16 MFMA (R15-exact): 128x128 tile, BK=64, SK=8,
// 1-deep in-place prefetch, trunc-split staging.
// ---------------------------------------------------------------------------
#define G1_LDS 73728
__device__ __forceinline__ int aofs(int r, int kb) { return r * 144 + kb; }
__device__ __forceinline__ int bofs(int n, int kb) { return n * 144 + (kb ^ (((n >> 3) & 1) << 4)); }

__global__ __launch_bounds__(512, 4) void gemm1_mfma(
    const float* __restrict__ Ag, const float* __restrict__ Bg,
    float* __restrict__ part)
{
    extern __shared__ char sm[];
    char* AH = sm;             // [128][144]
    char* AL = sm + 18432;
    char* BH = sm + 36864;     // [128][144]
    char* BL = sm + 55296;

    const int tid = threadIdx.x;
    const int pb = blockIdx.x;
    const int task = (pb & 7) * 64 + (pb >> 3);
    const int mb = task & 7, g = task >> 3;
    const int nb = g & 7, z = g >> 3;
    const int m0 = mb * 128, n0 = nb * 128;
    const int k0 = z * 1600;

    const int w = tid >> 6, lane = tid & 63;
    const int wn = w & 3, wm = w >> 2;               // wave tile 64m x 32n
    const int c16 = lane & 15, r16 = lane >> 4;

    const int ra = tid >> 2, kq = tid & 3;           // A: row, 16-k quarter
    const int bn = tid >> 2, kq4 = tid & 3;          // B: col n, 16-k quarter

    const float* Aptr = Ag + (size_t)(m0 + ra) * K1 + k0 + kq * 16;
    const float* Bptr = Bg + (size_t)(k0 + kq4 * 16) * N1 + n0 + bn;

    f32x4 acc[4][2];
    #pragma unroll
    for (int i = 0; i < 4; ++i)
        #pragma unroll
        for (int j = 0; j < 2; ++j) acc[i][j] = (f32x4){0.f, 0.f, 0.f, 0.f};

    float a_reg[16];
    float bR[16];
    #pragma unroll
    for (int q = 0; q < 4; ++q) *(float4*)&a_reg[q * 4] = *(const float4*)(Aptr + q * 4);
    #pragma unroll
    for (int j = 0; j < 16; ++j) bR[j] = Bptr[(size_t)j * N1];

    for (int it = 0; it < 25; ++it) {
        __syncthreads();   // previous iter's MFMA reads done -> LDS writable
        {   // A staging: trunc split + perm pack
            uint hi[8], lo[8];
            #pragma unroll
            for (int i = 0; i < 8; ++i) tsplit2(a_reg[2 * i], a_reg[2 * i + 1], hi[i], lo[i]);
            const int ab = aofs(ra, kq * 32);   // aofs has no XOR: +16 safe
            *(uint4*)(AH + ab)      = make_uint4(hi[0], hi[1], hi[2], hi[3]);
            *(uint4*)(AH + ab + 16) = make_uint4(hi[4], hi[5], hi[6], hi[7]);
            *(uint4*)(AL + ab)      = make_uint4(lo[0], lo[1], lo[2], lo[3]);
            *(uint4*)(AL + ab + 16) = make_uint4(lo[4], lo[5], lo[6], lo[7]);
        }
        {   // B staging: trunc split + perm pack (swizzle-aware per-16B)
            uint hi[8], lo[8];
            #pragma unroll
            for (int i = 0; i < 8; ++i) tsplit2(bR[2 * i], bR[2 * i + 1], hi[i], lo[i]);
            const int bb0 = bofs(bn, kq4 * 32);
            const int bb1 = bofs(bn, kq4 * 32 + 16);
            *(uint4*)(BH + bb0) = make_uint4(hi[0], hi[1], hi[2], hi[3]);
            *(uint4*)(BH + bb1) = make_uint4(hi[4], hi[5], hi[6], hi[7]);
            *(uint4*)(BL + bb0) = make_uint4(lo[0], lo[1], lo[2], lo[3]);
            *(uint4*)(BL + bb1) = make_uint4(lo[4], lo[5], lo[6], lo[7]);
        }
        __syncthreads();   // LDS tile ready

        if (it < 24) {     // prefetch next iter into the same regs
            const int off = (it + 1) * 64;
            #pragma unroll
            for (int q = 0; q < 4; ++q) *(float4*)&a_reg[q * 4] = *(const float4*)(Aptr + off + q * 4);
            #pragma unroll
            for (int j = 0; j < 16; ++j) bR[j] = Bptr[(size_t)(off + j) * N1];
        }

        #pragma unroll
        for (int ks = 0; ks < 2; ++ks) {
            const int kb = ks * 64 + r16 * 16;
            short8 bh[2], bl[2];
            #pragma unroll
            for (int nf = 0; nf < 2; ++nf) {
                const int nr = wn * 32 + nf * 16 + c16;
                bh[nf] = *(const short8*)(BH + bofs(nr, kb));
                bl[nf] = *(const short8*)(BL + bofs(nr, kb));
            }
            #pragma unroll
            for (int mf = 0; mf < 4; ++mf) {
                const int ar = wm * 64 + mf * 16 + c16;
                short8 ah = *(const short8*)(AH + aofs(ar, kb));
                short8 al = *(const short8*)(AL + aofs(ar, kb));
                #pragma unroll
                for (int nf = 0; nf < 2; ++nf) {
                    acc[mf][nf] = __builtin_amdgcn_mfma_f32_16x16x32_bf16(ah, bh[nf], acc[mf][nf], 0, 0, 0);
                    acc[mf][nf] = __builtin_amdgcn_mfma_f32_16x16x32_bf16(al, bh[nf], acc[mf][nf], 0, 0, 0);
                    acc[mf][nf] = __builtin_amdgcn_mfma_f32_16x16x32_bf16(ah, bl[nf], acc[mf][nf], 0, 0, 0);
                }
            }
        }
    }

    float* pz = part + (size_t)z * M1 * N1;
    #pragma unroll
    for (int mf = 0; mf < 4; ++mf) {
        const int m = m0 + wm * 64 + mf * 16 + r16 * 4;
        #pragma unroll
        for (int nf = 0; nf < 2; ++nf) {
            const int n = n0 + wn * 32 + nf * 16 + c16;
            #pragma unroll
            for (int r = 0; r < 4; ++r)
                pz[(size_t)(m + r) * N1 + n] = acc[mf][nf][r];
        }
    }
}

// Reduce split-K partials + bias + BN(eval) + ReLU
__global__ __launch_bounds__(256) void bn1_reduce(
    const float* __restrict__ part, const float* __restrict__ pb1,
    const float* __restrict__ g1, const float* __restrict__ be1,
    float* __restrict__ y1)
{
    const int idx = blockIdx.x * 256 + threadIdx.x;
    float s = 0.f;
    #pragma unroll
    for (int z = 0; z < SK; ++z) s += part[(size_t)z * M1 * N1 + idx];
    const int j = idx & (N1 - 1);
    s += pb1[j];
    const float rbn = 1.0f / sqrtf(1.0f + 1e-5f);
    s = g1[j] * s * rbn + be1[j];
    y1[idx] = fmaxf(s, 0.f);
}

// GEMM2 (1024x1024)x(1024x128) + bias + BN + ReLU -> d_out
__global__ __launch_bounds__(128) void gemm2_bn(
    const float* __restrict__ y1, const float* __restrict__ W2,
    const float* __restrict__ pb2, const float* __restrict__ g2,
    const float* __restrict__ be2, float* __restrict__ out)
{
    __shared__ __align__(16) float xr[1024];
    const int tid = threadIdx.x, m = blockIdx.x;
    for (int i = tid; i < 1024; i += 128) xr[i] = y1[(size_t)m * 1024 + i];
    __syncthreads();
    float acc = 0.f;
    #pragma unroll 8
    for (int k = 0; k < 1024; ++k) acc += xr[k] * W2[k * 128 + tid];
    acc += pb2[tid];
    const float rbn = 1.0f / sqrtf(1.0f + 1e-5f);
    acc = g2[tid] * acc * rbn + be2[tid];
    out[(size_t)m * 128 + tid] = fmaxf(acc, 0.f);
}

// ---------------------------------------------------------------------------
extern "C" void kernel_launch(void* const* d_in, const int* in_sizes, int n_in,
                              void* d_out, int out_size, void* d_ws, size_t ws_size,
                              hipStream_t stream)
{
    const float* X   = (const float*)d_in[0];
    const float* A   = (const float*)d_in[1];
    const float* W0  = (const float*)d_in[2];
    const float* a0  = (const float*)d_in[3];
    const float* Wl  = (const float*)d_in[4];
    const float* al  = (const float*)d_in[5];
    const float* pW1 = (const float*)d_in[6];
    const float* pb1 = (const float*)d_in[7];
    const float* g1  = (const float*)d_in[8];
    const float* be1 = (const float*)d_in[9];
    const float* pW2 = (const float*)d_in[10];
    const float* pb2 = (const float*)d_in[11];
    const float* g2  = (const float*)d_in[12];
    const float* be2 = (const float*)d_in[13];
    float* out = (float*)d_out;

    // ws: xa(52.4MB) | xb(52.4MB, reused as gemm1 partials) | y1(4.2MB, AW overlay)
    float* ws = (float*)d_ws;
    float* xa = ws;
    float* xb = xa + (size_t)Bb * Nn * Dd;
    float* y1 = xb + (size_t)Bb * Nn * Dd;
    float* part = xb;
    uint*  AW = (uint*)y1;          // packed adjacency, dead before bn1 writes y1

    (void)hipFuncSetAttribute(reinterpret_cast<const void*>(gat_fused<65, 3>),
                              hipFuncAttributeMaxDynamicSharedMemorySize, GAT_LDS);
    (void)hipFuncSetAttribute(reinterpret_cast<const void*>(gat_fused<128, 4>),
                              hipFuncAttributeMaxDynamicSharedMemorySize, GAT_LDS);
    (void)hipFuncSetAttribute(reinterpret_cast<const void*>(gemm1_mfma),
                              hipFuncAttributeMaxDynamicSharedMemorySize, G1_LDS);

    pack_A<<<dim3(Bb), 256, 0, stream>>>(A, AW);
    gat_fused<65, 3><<<dim3(Bb * Hh), 512, GAT_LDS, stream>>>(X, AW, W0, a0, xa);
    const float* src = xa; float* dst = xb;
    for (int l = 1; l < 5; ++l) {
        gat_fused<128, 4><<<dim3(Bb * Hh), 512, GAT_LDS, stream>>>(
            src, AW, Wl + (size_t)(l - 1) * Hh * Dd * Oo, al + (size_t)(l - 1) * Hh * 2 * Oo, dst);
        float* t = (float*)src; src = dst; dst = t;
    }
    // after 4 swaps final GAT output is xa; xb free for partials
    gemm1_mfma<<<dim3(512), 512, G1_LDS, stream>>>(xa, pW1, part);
    bn1_reduce<<<dim3((M1 * N1) / 256), 256, 0, stream>>>(part, pb1, g1, be1, y1);
    gemm2_bn<<<dim3(M1), 128, 0, stream>>>(y1, pW2, pb2, g2, be2, out);
}

// Round 19
// 451.103 us; speedup vs baseline: 1.1211x; 1.0142x over previous
//
#include <hip/hip_runtime.h>
#include <math.h>

typedef __attribute__((ext_vector_type(8))) short short8;   // 8 bf16 (4 VGPR) MFMA A/B frag
typedef __attribute__((ext_vector_type(4))) float f32x4;    // MFMA C/D frag
typedef __attribute__((ext_vector_type(4))) uint  uint4v;

constexpr int Bb = 1024, Nn = 100, Hh = 4, Oo = 32, Dd = 128;
constexpr int K1 = 12800, N1 = 1024, M1 = 1024, SK = 8;

#define SEL_L 0x07060302u   /* perm: high ushorts of (b,a) -> packed trunc-bf16 pair */
#define LOG2E 1.44269504f

// bf16 round-to-nearest-even helpers (cold paths only)
__device__ __forceinline__ ushort f2bf(float f) {
    uint u = __float_as_uint(f);
    return (ushort)((u + 0x7FFFu + ((u >> 16) & 1u)) >> 16);
}
__device__ __forceinline__ float bf2f(ushort h) {
    return __uint_as_float(((uint)h) << 16);
}
__device__ __forceinline__ short8 mk8(uint a, uint b, uint c, uint d) {
    uint4v v = {a, b, c, d};
    return __builtin_bit_cast(short8, v);
}
// trunc-split a pair of floats -> packed hi-pair and lo-pair (6 VALU per pair)
__device__ __forceinline__ void tsplit2(float v0, float v1, uint& hp, uint& lp) {
    uint u0 = __float_as_uint(v0), u1 = __float_as_uint(v1);
    float r0 = v0 - __uint_as_float(u0 & 0xFFFF0000u);
    float r1 = v1 - __uint_as_float(u1 & 0xFFFF0000u);
    hp = __builtin_amdgcn_perm(u1, u0, SEL_L);
    lp = __builtin_amdgcn_perm(__float_as_uint(r1), __float_as_uint(r0), SEL_L);
}
// swizzle within [rows][256B] LDS tiles: XOR 16B-slot bits with row&7
__device__ __forceinline__ int swzb(int row, int kb)  { return row * 256 + (kb ^ ((row & 7) << 4)); }

// GAT LDS layout (dynamic, 36352 B)
#define OFF_HTH 0        /* hT hi [32][256B] */
#define OFF_HTL 8192
#define OFF_WTH 16384    /* WT hi [32][256B] */
#define OFF_WTL 24576
#define OFF_AB  32768    /* adjacency bitmask [112][4 u32] (448 words, >=400 zeroed) */
#define OFF_ASV 34560    /* a-vector 64 f32 (pre-scaled by log2 e) */
#define OFF_ESV 34816    /* e_src [128] f32 */
#define OFF_EDV 35328    /* e_dst [128] f32 */
#define OFF_INV 35840    /* 1/rowsum [128] f32 */
#define GAT_LDS 36352

// ---------------------------------------------------------------------------
// pack_A: adjacency -> 128-bit masks, once per b (not per head).
// ---------------------------------------------------------------------------
__global__ __launch_bounds__(256) void pack_A(const float* __restrict__ A, uint* __restrict__ AW)
{
    const int b = blockIdx.x;
    const float4* Ab = (const float4*)(A + (size_t)b * 10000);
    for (int t = threadIdx.x; t < 400; t += 256) {
        const int row = t >> 2, word = t & 3;
        uint bits = 0;
        if (word < 3) {
            #pragma unroll
            for (int j = 0; j < 8; ++j) {
                float4 v = Ab[row * 25 + word * 8 + j];
                uint b4 = (v.x > 0.f ? 1u : 0u) | (v.y > 0.f ? 2u : 0u)
                        | (v.z > 0.f ? 4u : 0u) | (v.w > 0.f ? 8u : 0u);
                bits |= b4 << (j * 4);
            }
        } else {
            float4 v = Ab[row * 25 + 24];   // cols 96..99; 100..127 stay 0
            bits = (v.x > 0.f ? 1u : 0u) | (v.y > 0.f ? 2u : 0u)
                 | (v.z > 0.f ? 4u : 0u) | (v.w > 0.f ? 8u : 0u);
        }
        AW[(size_t)b * 400 + t] = bits;
    }
}

// ---------------------------------------------------------------------------
// Fused GAT layer v3.2 (R15-exact): per (b, head) block, 512 thr, 3 barriers;
//   in-register P -> MFMA-2; trunc-split packing + exp2 softmax.
// ---------------------------------------------------------------------------
template<int F, int KD>
__global__ __launch_bounds__(512, 4) void gat_fused(
    const float* __restrict__ xin,   // [B][100][F]
    const uint*  __restrict__ AW,    // [B][100][4] packed adjacency
    const float* __restrict__ W,     // [H][F][32]
    const float* __restrict__ av,    // [H][64]
    float* __restrict__ xout)        // [B][100][128]
{
    extern __shared__ char smem[];
    char*  HTH = smem + OFF_HTH;
    char*  HTL = smem + OFF_HTL;
    char*  WTH = smem + OFF_WTH;
    char*  WTL = smem + OFF_WTL;
    uint*  ABu = (uint*)(smem + OFF_AB);
    float* ASV = (float*)(smem + OFF_ASV);
    float* ESV = (float*)(smem + OFF_ESV);
    float* EDV = (float*)(smem + OFF_EDV);
    float* INV = (float*)(smem + OFF_INV);

    const int tid = threadIdx.x;
    // XCD-grouped swizzle: 4 head-blocks of one b land on one XCD, adjacent slots
    const int task = (blockIdx.x & 7) * 512 + (blockIdx.x >> 3);
    const int b = task >> 2, hd = task & 3;
    const int w = tid >> 6, lane = tid & 63;
    const int c16 = lane & 15, r16 = lane >> 4;

    const float* xg = xin + (size_t)b * Nn * F;

    if (F == 65) {   // zero WT for k-padding (f 65..95)
        uint4 z = make_uint4(0, 0, 0, 0);
        #pragma unroll
        for (int i = 0; i < 2; ++i)
            *(uint4*)(smem + OFF_WTH + (i * 512 + tid) * 16) = z;
        __syncthreads();
    }

    // ---- prefetch x fragments (F=128 path) before the staging barrier
    const int nA = (w * 16 + c16 < 100) ? (w * 16 + c16) : 99;
    float4 xpre[8];
    if (F == 128 && w < 7) {
        #pragma unroll
        for (int d = 0; d < 4; ++d) {
            const float* px = xg + (size_t)nA * 128 + d * 32 + r16 * 8;
            xpre[2 * d]     = *(const float4*)(px);
            xpre[2 * d + 1] = *(const float4*)(px + 4);
        }
    }

    // ---- ph1: stage WT (RNE hi/lo, transposed; cold), ASV (pre-scaled), AB, zero tails
    {
        const float4* Wg4 = (const float4*)(W + (size_t)hd * F * 32);
        #pragma unroll
        for (int it = 0; it < 2; ++it) {
            int id = it * 512 + tid;            // F*8 chunks (f, o4)
            if (id < F * 8) {
                int f = id >> 3, o4 = (id & 7) * 4;
                float4 v = Wg4[id];
                ushort h0 = f2bf(v.x), l0 = f2bf(v.x - bf2f(h0));
                ushort h1 = f2bf(v.y), l1 = f2bf(v.y - bf2f(h1));
                ushort h2 = f2bf(v.z), l2 = f2bf(v.z - bf2f(h2));
                ushort h3 = f2bf(v.w), l3 = f2bf(v.w - bf2f(h3));
                *(ushort*)(WTH + swzb(o4 + 0, 2 * f)) = h0; *(ushort*)(WTL + swzb(o4 + 0, 2 * f)) = l0;
                *(ushort*)(WTH + swzb(o4 + 1, 2 * f)) = h1; *(ushort*)(WTL + swzb(o4 + 1, 2 * f)) = l1;
                *(ushort*)(WTH + swzb(o4 + 2, 2 * f)) = h2; *(ushort*)(WTL + swzb(o4 + 2, 2 * f)) = l2;
                *(ushort*)(WTH + swzb(o4 + 3, 2 * f)) = h3; *(ushort*)(WTL + swzb(o4 + 3, 2 * f)) = l3;
            }
        }
    }
    if (tid < 64) ASV[tid] = av[hd * 64 + tid] * LOG2E;   // fold exp->exp2 scale
    {
        const int idA = tid - 64;
        if (idA >= 0 && idA < 400) ABu[idA] = AW[(size_t)b * 400 + idA];
        else if (idA >= 400 && idA < 448) ABu[idA] = 0u;   // rows 100..111 -> mask 0
    }
    if (tid < 256) {    // zero hT cols 96..127 (96..99 rewritten in ph2)
        char* base = (tid & 128) ? HTL : HTH;
        const int rr = (tid >> 2) & 31, sl = 12 + (tid & 3);
        *(uint4*)(base + swzb(rr, sl * 16)) = make_uint4(0, 0, 0, 0);
    }
    if (tid < 28) { ESV[100 + tid] = 0.f; EDV[100 + tid] = 0.f; }
    __syncthreads();

    // ---- ph2: MFMA-1 h = x*W (wave w owns rows w*16..+15, both o-halves)
    if (w < 7) {
        f32x4 acc0 = {0.f, 0.f, 0.f, 0.f}, acc1 = {0.f, 0.f, 0.f, 0.f};
        #pragma unroll
        for (int d = 0; d < KD; ++d) {
            float xv[8];
            if (F == 128) {
                float4 v0 = xpre[2 * d], v1 = xpre[2 * d + 1];
                xv[0] = v0.x; xv[1] = v0.y; xv[2] = v0.z; xv[3] = v0.w;
                xv[4] = v1.x; xv[5] = v1.y; xv[6] = v1.z; xv[7] = v1.w;
            } else {
                const int f0 = d * 32 + r16 * 8;
                #pragma unroll
                for (int j = 0; j < 8; ++j) {
                    int f = f0 + j;
                    xv[j] = (f < 65) ? xg[(size_t)nA * 65 + f] : 0.f;
                }
            }
            uint hu[4], lu[4];
            tsplit2(xv[0], xv[1], hu[0], lu[0]);
            tsplit2(xv[2], xv[3], hu[1], lu[1]);
            tsplit2(xv[4], xv[5], hu[2], lu[2]);
            tsplit2(xv[6], xv[7], hu[3], lu[3]);
            short8 ah = mk8(hu[0], hu[1], hu[2], hu[3]);
            short8 al = mk8(lu[0], lu[1], lu[2], lu[3]);
            const int kb = d * 64 + r16 * 16;
            short8 bh0 = *(const short8*)(WTH + swzb(c16, kb));
            short8 bl0 = *(const short8*)(WTL + swzb(c16, kb));
            short8 bh1 = *(const short8*)(WTH + swzb(16 + c16, kb));
            short8 bl1 = *(const short8*)(WTL + swzb(16 + c16, kb));
            acc0 = __builtin_amdgcn_mfma_f32_16x16x32_bf16(ah, bh0, acc0, 0, 0, 0);
            acc0 = __builtin_amdgcn_mfma_f32_16x16x32_bf16(al, bh0, acc0, 0, 0, 0);
            acc0 = __builtin_amdgcn_mfma_f32_16x16x32_bf16(ah, bl0, acc0, 0, 0, 0);
            acc1 = __builtin_amdgcn_mfma_f32_16x16x32_bf16(ah, bh1, acc1, 0, 0, 0);
            acc1 = __builtin_amdgcn_mfma_f32_16x16x32_bf16(al, bh1, acc1, 0, 0, 0);
            acc1 = __builtin_amdgcn_mfma_f32_16x16x32_bf16(ah, bl1, acc1, 0, 0, 0);
        }
        const int n0 = w * 16 + r16 * 4;
        if (n0 < 100) {   // hT trunc-split write: rows o, cols n0..n0+3
            uint2 uh, ul;
            tsplit2(acc0[0], acc0[1], uh.x, ul.x);
            tsplit2(acc0[2], acc0[3], uh.y, ul.y);
            *(uint2*)(HTH + swzb(c16, 2 * n0)) = uh;
            *(uint2*)(HTL + swzb(c16, 2 * n0)) = ul;
            tsplit2(acc1[0], acc1[1], uh.x, ul.x);
            tsplit2(acc1[2], acc1[3], uh.y, ul.y);
            *(uint2*)(HTH + swzb(16 + c16, 2 * n0)) = uh;
            *(uint2*)(HTL + swzb(16 + c16, 2 * n0)) = ul;
        }
        // es/ed: reduce acc*a over 32 o's (both halves pre-summed, 16-lane xor)
        const float as0 = ASV[c16], as1 = ASV[16 + c16];
        const float ad0 = ASV[32 + c16], ad1 = ASV[48 + c16];
        #pragma unroll
        for (int r = 0; r < 4; ++r) {
            float vs = acc0[r] * as0 + acc1[r] * as1;
            float vd = acc0[r] * ad0 + acc1[r] * ad1;
            #pragma unroll
            for (int mk = 1; mk <= 8; mk <<= 1) {
                vs += __shfl_xor(vs, mk, 64);
                vd += __shfl_xor(vd, mk, 64);
            }
            if (c16 == 0 && n0 + r < 100) { ESV[n0 + r] = vs; EDV[n0 + r] = vd; }
        }
    }
    __syncthreads();

    // ---- ph3a: in-register P (exp2, trunc-split), MFMA-2; rowsum -> INV (LDS)
    f32x4 acc0 = {0.f, 0.f, 0.f, 0.f}, acc1 = {0.f, 0.f, 0.f, 0.f};
    if (w < 7) {
        const int np = w * 16 + c16;            // P-row this lane supplies (<=111)
        const float esn = ESV[np];
        const uint4 abv = *(const uint4*)(ABu + np * 4);
        float rowsum = 0.f;
        #pragma unroll
        for (int d = 0; d < 4; ++d) {
            const uint wrd = (d == 0) ? abv.x : (d == 1) ? abv.y : (d == 2) ? abv.z : abv.w;
            const float4 ea = *(const float4*)(EDV + d * 32 + r16 * 8);
            const float4 eb = *(const float4*)(EDV + d * 32 + r16 * 8 + 4);
            float p0, p1, p2, p3, p4, p5, p6, p7, e;
            e = esn + ea.x; e = fmaxf(e, 0.2f * e); p0 = ((wrd >> (r16 * 8 + 0)) & 1u) ? exp2f(e) : 0.f;
            e = esn + ea.y; e = fmaxf(e, 0.2f * e); p1 = ((wrd >> (r16 * 8 + 1)) & 1u) ? exp2f(e) : 0.f;
            e = esn + ea.z; e = fmaxf(e, 0.2f * e); p2 = ((wrd >> (r16 * 8 + 2)) & 1u) ? exp2f(e) : 0.f;
            e = esn + ea.w; e = fmaxf(e, 0.2f * e); p3 = ((wrd >> (r16 * 8 + 3)) & 1u) ? exp2f(e) : 0.f;
            e = esn + eb.x; e = fmaxf(e, 0.2f * e); p4 = ((wrd >> (r16 * 8 + 4)) & 1u) ? exp2f(e) : 0.f;
            e = esn + eb.y; e = fmaxf(e, 0.2f * e); p5 = ((wrd >> (r16 * 8 + 5)) & 1u) ? exp2f(e) : 0.f;
            e = esn + eb.z; e = fmaxf(e, 0.2f * e); p6 = ((wrd >> (r16 * 8 + 6)) & 1u) ? exp2f(e) : 0.f;
            e = esn + eb.w; e = fmaxf(e, 0.2f * e); p7 = ((wrd >> (r16 * 8 + 7)) & 1u) ? exp2f(e) : 0.f;
            rowsum += p0 + p1 + p2 + p3 + p4 + p5 + p6 + p7;
            uint h01, l01, h23, l23, h45, l45, h67, l67;
            tsplit2(p0, p1, h01, l01);
            tsplit2(p2, p3, h23, l23);
            tsplit2(p4, p5, h45, l45);
            tsplit2(p6, p7, h67, l67);
            short8 ph = mk8(h01, h23, h45, h67);
            short8 pl = mk8(l01, l23, l45, l67);
            const int kb = d * 64 + r16 * 16;
            short8 bh0 = *(const short8*)(HTH + swzb(c16, kb));
            short8 bl0 = *(const short8*)(HTL + swzb(c16, kb));
            short8 bh1 = *(const short8*)(HTH + swzb(16 + c16, kb));
            short8 bl1 = *(const short8*)(HTL + swzb(16 + c16, kb));
            acc0 = __builtin_amdgcn_mfma_f32_16x16x32_bf16(ph, bh0, acc0, 0, 0, 0);
            acc0 = __builtin_amdgcn_mfma_f32_16x16x32_bf16(ph, bl0, acc0, 0, 0, 0);
            acc0 = __builtin_amdgcn_mfma_f32_16x16x32_bf16(pl, bh0, acc0, 0, 0, 0);
            acc1 = __builtin_amdgcn_mfma_f32_16x16x32_bf16(ph, bh1, acc1, 0, 0, 0);
            acc1 = __builtin_amdgcn_mfma_f32_16x16x32_bf16(ph, bl1, acc1, 0, 0, 0);
            acc1 = __builtin_amdgcn_mfma_f32_16x16x32_bf16(pl, bh1, acc1, 0, 0, 0);
        }
        rowsum += __shfl_xor(rowsum, 16, 64);
        rowsum += __shfl_xor(rowsum, 32, 64);
        if (r16 == 0 && np < 100) INV[np] = 1.0f / rowsum;
    }
    __syncthreads();

    // ---- ph3b: epilogue elu(acc * inv) -> global fp32
    if (w < 7) {
        const int n0 = w * 16 + r16 * 4;
        float* xo = xout + (size_t)b * Nn * Dd + hd * 32;
        #pragma unroll
        for (int r = 0; r < 4; ++r) {
            const int n = n0 + r;
            if (n < 100) {
                const float inv = INV[n];
                float v0 = acc0[r] * inv; v0 = v0 > 0.f ? v0 : expm1f(v0);
                float v1 = acc1[r] * inv; v1 = v1 > 0.f ? v1 : expm1f(v1);
                xo[(size_t)n * Dd + c16] = v0;
                xo[(size_t)n * Dd + 16 + c16] = v1;
            }
        }
    }
}

// ---------------------------------------------------------------------------
// GEMM1 split-bf16 MFMA (R15-exact): 128x128 tile, BK=64, SK=8,
// 1-deep in-place prefetch, trunc-split staging.
// ---------------------------------------------------------------------------
#define G1_LDS 73728
__device__ __forceinline__ int aofs(int r, int kb) { return r * 144 + kb; }
__device__ __forceinline__ int bofs(int n, int kb) { return n * 144 + (kb ^ (((n >> 3) & 1) << 4)); }

__global__ __launch_bounds__(512, 4) void gemm1_mfma(
    const float* __restrict__ Ag, const float* __restrict__ Bg,
    float* __restrict__ part)
{
    extern __shared__ char sm[];
    char* AH = sm;             // [128][144]
    char* AL = sm + 18432;
    char* BH = sm + 36864;     // [128][144]
    char* BL = sm + 55296;

    const int tid = threadIdx.x;
    const int pb = blockIdx.x;
    const int task = (pb & 7) * 64 + (pb >> 3);
    const int mb = task & 7, g = task >> 3;
    const int nb = g & 7, z = g >> 3;
    const int m0 = mb * 128, n0 = nb * 128;
    const int k0 = z * 1600;

    const int w = tid >> 6, lane = tid & 63;
    const int wn = w & 3, wm = w >> 2;               // wave tile 64m x 32n
    const int c16 = lane & 15, r16 = lane >> 4;

    const int ra = tid >> 2, kq = tid & 3;           // A: row, 16-k quarter
    const int bn = tid >> 2, kq4 = tid & 3;          // B: col n, 16-k quarter

    const float* Aptr = Ag + (size_t)(m0 + ra) * K1 + k0 + kq * 16;
    const float* Bptr = Bg + (size_t)(k0 + kq4 * 16) * N1 + n0 + bn;

    f32x4 acc[4][2];
    #pragma unroll
    for (int i = 0; i < 4; ++i)
        #pragma unroll
        for (int j = 0; j < 2; ++j) acc[i][j] = (f32x4){0.f, 0.f, 0.f, 0.f};

    float a_reg[16];
    float bR[16];
    #pragma unroll
    for (int q = 0; q < 4; ++q) *(float4*)&a_reg[q * 4] = *(const float4*)(Aptr + q * 4);
    #pragma unroll
    for (int j = 0; j < 16; ++j) bR[j] = Bptr[(size_t)j * N1];

    for (int it = 0; it < 25; ++it) {
        __syncthreads();   // previous iter's MFMA reads done -> LDS writable
        {   // A staging: trunc split + perm pack
            uint hi[8], lo[8];
            #pragma unroll
            for (int i = 0; i < 8; ++i) tsplit2(a_reg[2 * i], a_reg[2 * i + 1], hi[i], lo[i]);
            const int ab = aofs(ra, kq * 32);   // aofs has no XOR: +16 safe
            *(uint4*)(AH + ab)      = make_uint4(hi[0], hi[1], hi[2], hi[3]);
            *(uint4*)(AH + ab + 16) = make_uint4(hi[4], hi[5], hi[6], hi[7]);
            *(uint4*)(AL + ab)      = make_uint4(lo[0], lo[1], lo[2], lo[3]);
            *(uint4*)(AL + ab + 16) = make_uint4(lo[4], lo[5], lo[6], lo[7]);
        }
        {   // B staging: trunc split + perm pack (swizzle-aware per-16B)
            uint hi[8], lo[8];
            #pragma unroll
            for (int i = 0; i < 8; ++i) tsplit2(bR[2 * i], bR[2 * i + 1], hi[i], lo[i]);
            const int bb0 = bofs(bn, kq4 * 32);
            const int bb1 = bofs(bn, kq4 * 32 + 16);
            *(uint4*)(BH + bb0) = make_uint4(hi[0], hi[1], hi[2], hi[3]);
            *(uint4*)(BH + bb1) = make_uint4(hi[4], hi[5], hi[6], hi[7]);
            *(uint4*)(BL + bb0) = make_uint4(lo[0], lo[1], lo[2], lo[3]);
            *(uint4*)(BL + bb1) = make_uint4(lo[4], lo[5], lo[6], lo[7]);
        }
        __syncthreads();   // LDS tile ready

        if (it < 24) {     // prefetch next iter into the same regs
            const int off = (it + 1) * 64;
            #pragma unroll
            for (int q = 0; q < 4; ++q) *(float4*)&a_reg[q * 4] = *(const float4*)(Aptr + off + q * 4);
            #pragma unroll
            for (int j = 0; j < 16; ++j) bR[j] = Bptr[(size_t)(off + j) * N1];
        }

        #pragma unroll
        for (int ks = 0; ks < 2; ++ks) {
            const int kb = ks * 64 + r16 * 16;
            short8 bh[2], bl[2];
            #pragma unroll
            for (int nf = 0; nf < 2; ++nf) {
                const int nr = wn * 32 + nf * 16 + c16;
                bh[nf] = *(const short8*)(BH + bofs(nr, kb));
                bl[nf] = *(const short8*)(BL + bofs(nr, kb));
            }
            #pragma unroll
            for (int mf = 0; mf < 4; ++mf) {
                const int ar = wm * 64 + mf * 16 + c16;
                short8 ah = *(const short8*)(AH + aofs(ar, kb));
                short8 al = *(const short8*)(AL + aofs(ar, kb));
                #pragma unroll
                for (int nf = 0; nf < 2; ++nf) {
                    acc[mf][nf] = __builtin_amdgcn_mfma_f32_16x16x32_bf16(ah, bh[nf], acc[mf][nf], 0, 0, 0);
                    acc[mf][nf] = __builtin_amdgcn_mfma_f32_16x16x32_bf16(al, bh[nf], acc[mf][nf], 0, 0, 0);
                    acc[mf][nf] = __builtin_amdgcn_mfma_f32_16x16x32_bf16(ah, bl[nf], acc[mf][nf], 0, 0, 0);
                }
            }
        }
    }

    float* pz = part + (size_t)z * M1 * N1;
    #pragma unroll
    for (int mf = 0; mf < 4; ++mf) {
        const int m = m0 + wm * 64 + mf * 16 + r16 * 4;
        #pragma unroll
        for (int nf = 0; nf < 2; ++nf) {
            const int n = n0 + wn * 32 + nf * 16 + c16;
            #pragma unroll
            for (int r = 0; r < 4; ++r)
                pz[(size_t)(m + r) * N1 + n] = acc[mf][nf][r];
        }
    }
}

// Reduce split-K partials + bias + BN(eval) + ReLU
__global__ __launch_bounds__(256) void bn1_reduce(
    const float* __restrict__ part, const float* __restrict__ pb1,
    const float* __restrict__ g1, const float* __restrict__ be1,
    float* __restrict__ y1)
{
    const int idx = blockIdx.x * 256 + threadIdx.x;
    float s = 0.f;
    #pragma unroll
    for (int z = 0; z < SK; ++z) s += part[(size_t)z * M1 * N1 + idx];
    const int j = idx & (N1 - 1);
    s += pb1[j];
    const float rbn = 1.0f / sqrtf(1.0f + 1e-5f);
    s = g1[j] * s * rbn + be1[j];
    y1[idx] = fmaxf(s, 0.f);
}

// GEMM2 (1024x1024)x(1024x128) + bias + BN + ReLU -> d_out
__global__ __launch_bounds__(128) void gemm2_bn(
    const float* __restrict__ y1, const float* __restrict__ W2,
    const float* __restrict__ pb2, const float* __restrict__ g2,
    const float* __restrict__ be2, float* __restrict__ out)
{
    __shared__ __align__(16) float xr[1024];
    const int tid = threadIdx.x, m = blockIdx.x;
    for (int i = tid; i < 1024; i += 128) xr[i] = y1[(size_t)m * 1024 + i];
    __syncthreads();
    float acc = 0.f;
    #pragma unroll 8
    for (int k = 0; k < 1024; ++k) acc += xr[k] * W2[k * 128 + tid];
    acc += pb2[tid];
    const float rbn = 1.0f / sqrtf(1.0f + 1e-5f);
    acc = g2[tid] * acc * rbn + be2[tid];
    out[(size_t)m * 128 + tid] = fmaxf(acc, 0.f);
}

// ---------------------------------------------------------------------------
extern "C" void kernel_launch(void* const* d_in, const int* in_sizes, int n_in,
                              void* d_out, int out_size, void* d_ws, size_t ws_size,
                              hipStream_t stream)
{
    const float* X   = (const float*)d_in[0];
    const float* A   = (const float*)d_in[1];
    const float* W0  = (const float*)d_in[2];
    const float* a0  = (const float*)d_in[3];
    const float* Wl  = (const float*)d_in[4];
    const float* al  = (const float*)d_in[5];
    const float* pW1 = (const float*)d_in[6];
    const float* pb1 = (const float*)d_in[7];
    const float* g1  = (const float*)d_in[8];
    const float* be1 = (const float*)d_in[9];
    const float* pW2 = (const float*)d_in[10];
    const float* pb2 = (const float*)d_in[11];
    const float* g2  = (const float*)d_in[12];
    const float* be2 = (const float*)d_in[13];
    float* out = (float*)d_out;

    // ws: xa(52.4MB) | xb(52.4MB, reused as gemm1 partials) | y1(4.2MB, AW overlay)
    float* ws = (float*)d_ws;
    float* xa = ws;
    float* xb = xa + (size_t)Bb * Nn * Dd;
    float* y1 = xb + (size_t)Bb * Nn * Dd;
    float* part = xb;
    uint*  AW = (uint*)y1;          // packed adjacency, dead before bn1 writes y1

    (void)hipFuncSetAttribute(reinterpret_cast<const void*>(gat_fused<65, 3>),
                              hipFuncAttributeMaxDynamicSharedMemorySize, GAT_LDS);
    (void)hipFuncSetAttribute(reinterpret_cast<const void*>(gat_fused<128, 4>),
                              hipFuncAttributeMaxDynamicSharedMemorySize, GAT_LDS);
    (void)hipFuncSetAttribute(reinterpret_cast<const void*>(gemm1_mfma),
                              hipFuncAttributeMaxDynamicSharedMemorySize, G1_LDS);

    pack_A<<<dim3(Bb), 256, 0, stream>>>(A, AW);
    gat_fused<65, 3><<<dim3(Bb * Hh), 512, GAT_LDS, stream>>>(X, AW, W0, a0, xa);
    const float* src = xa; float* dst = xb;
    for (int l = 1; l < 5; ++l) {
        gat_fused<128, 4><<<dim3(Bb * Hh), 512, GAT_LDS, stream>>>(
            src, AW, Wl + (size_t)(l - 1) * Hh * Dd * Oo, al + (size_t)(l - 1) * Hh * 2 * Oo, dst);
        float* t = (float*)src; src = dst; dst = t;
    }
    // after 4 swaps final GAT output is xa; xb free for partials
    gemm1_mfma<<<dim3(512), 512, G1_LDS, stream>>>(xa, pW1, part);
    bn1_reduce<<<dim3((M1 * N1) / 256), 256, 0, stream>>>(part, pb1, g1, be1, y1);
    gemm2_bn<<<dim3(M1), 128, 0, stream>>>(y1, pW2, pb2, g2, be2, out);
}